// Round 18
// baseline (231.630 us; speedup 1.0000x reference)
//
#include <hip/hip_runtime.h>
#include <hip/hip_bf16.h>

#define DEV __device__ __forceinline__

typedef __attribute__((ext_vector_type(4))) float f32x4;
typedef __attribute__((ext_vector_type(8))) __bf16 bf16x8;
typedef __attribute__((ext_vector_type(8))) unsigned short u16x8;
typedef __attribute__((ext_vector_type(4))) unsigned short u16x4;

// round-to-nearest-even f32 -> bf16
DEV unsigned short f2b(float x) {
  unsigned int u = __builtin_bit_cast(unsigned int, x);
  unsigned int r = (u + 0x7fffu + ((u >> 16) & 1u)) >> 16;
  return (unsigned short)r;
}

// packed f32x2 -> bf16x2 (RNE), single instruction
DEV unsigned int cvtpk(float a, float b) {
  unsigned int r;
  asm("v_cvt_pk_bf16_f32 %0, %1, %2" : "=v"(r) : "v"(a), "v"(b));
  return r;
}

DEV f32x4 mfma16(u16x8 a, u16x8 b, f32x4 c) {
  return __builtin_amdgcn_mfma_f32_16x16x32_bf16(
      __builtin_bit_cast(bf16x8, a), __builtin_bit_cast(bf16x8, b), c, 0, 0, 0);
}

// async global->LDS, 16B per lane; LDS dest is wave-uniform base + lane*16
DEV void async16(const unsigned short* g, unsigned short* l) {
  __builtin_amdgcn_global_load_lds(
      (const __attribute__((address_space(1))) void*)g,
      (__attribute__((address_space(3))) void*)l, 16, 0, 0);
}

// ---------------- conversion / transpose ----------------

__global__ void k_convert(const float* __restrict__ in, unsigned short* __restrict__ out, int n8) {
  int i = blockIdx.x * 256 + threadIdx.x;
  if (i >= n8) return;
  const float4* p = (const float4*)in + (size_t)i * 2;
  float4 a = p[0], b = p[1];
  u16x8 v;
  v[0] = f2b(a.x); v[1] = f2b(a.y); v[2] = f2b(a.z); v[3] = f2b(a.w);
  v[4] = f2b(b.x); v[5] = f2b(b.y); v[6] = f2b(b.z); v[7] = f2b(b.w);
  *((u16x8*)out + i) = v;
}

// in[R][Cc] f32 -> out[Cc][R] bf16
__global__ void k_transpose(const float* __restrict__ in, unsigned short* __restrict__ out,
                            int R, int Cc) {
  __shared__ float tile[32][33];
  int bx = blockIdx.x * 32, by = blockIdx.y * 32;
  int tx = threadIdx.x, ty = threadIdx.y;
#pragma unroll
  for (int i = 0; i < 32; i += 8)
    tile[ty + i][tx] = in[(size_t)(by + ty + i) * Cc + bx + tx];
  __syncthreads();
#pragma unroll
  for (int i = 0; i < 32; i += 8)
    out[(size_t)(bx + ty + i) * R + by + tx] = f2b(tile[tx][ty + i]);
}

// ---------------- GEMM: C[M][N] = A[M][K] * Bt[N][K]^T ----------------

template <typename OutT>
__global__ __launch_bounds__(256, 2)
void k_gemm_bt(const unsigned short* __restrict__ A, const unsigned short* __restrict__ Bt,
               OutT* __restrict__ C, int M, int N, int K, int ldc) {
  __shared__ __align__(16) unsigned short As[128 * 32];
  __shared__ __align__(16) unsigned short Bs[128 * 32];
  const int tid = threadIdx.x;
  const int w = tid >> 6, l = tid & 63;
  const int wr = w >> 1, wc = w & 1;
  const int lo = l & 15, hi = l >> 4;
  const int m0 = blockIdx.y * 128, n0 = blockIdx.x * 128;
  const int srow = l >> 2;            // row within 16-row segment
  const int scol = (l & 3) * 8;       // k elements
  const size_t a_base = (size_t)(m0 + 2 * w * 16 + srow) * K + scol;
  const size_t b_base = (size_t)(n0 + 2 * w * 16 + srow) * K + scol;

  f32x4 acc[4][4] = {};

  for (int kt = 0; kt < K; kt += 32) {
    async16(A + a_base + kt, &As[(2 * w) * 512]);
    async16(A + a_base + kt + (size_t)16 * K, &As[(2 * w + 1) * 512]);
    async16(Bt + b_base + kt, &Bs[(2 * w) * 512]);
    async16(Bt + b_base + kt + (size_t)16 * K, &Bs[(2 * w + 1) * 512]);
    __syncthreads();
    u16x8 af[4], bfv[4];
#pragma unroll
    for (int mi = 0; mi < 4; ++mi)
      af[mi] = *(const u16x8*)&As[(wr * 64 + mi * 16 + lo) * 32 + hi * 8];
#pragma unroll
    for (int ni = 0; ni < 4; ++ni)
      bfv[ni] = *(const u16x8*)&Bs[(wc * 64 + ni * 16 + lo) * 32 + hi * 8];
#pragma unroll
    for (int mi = 0; mi < 4; ++mi)
#pragma unroll
      for (int ni = 0; ni < 4; ++ni)
        acc[mi][ni] = mfma16(af[mi], bfv[ni], acc[mi][ni]);
    __syncthreads();
  }
#pragma unroll
  for (int mi = 0; mi < 4; ++mi) {
#pragma unroll
    for (int ni = 0; ni < 4; ++ni) {
      int col = n0 + wc * 64 + ni * 16 + lo;
#pragma unroll
      for (int r = 0; r < 4; ++r) {
        int row = m0 + wr * 64 + mi * 16 + hi * 4 + r;
        float v = acc[mi][ni][r];
        if constexpr (sizeof(OutT) == 4)
          C[(size_t)row * ldc + col] = v;
        else
          C[(size_t)row * ldc + col] = f2b(v);
      }
    }
  }
}

// ---- QKV GEMM with fused repack epilogue: writes Q,K [BH][T][D] and
// V^T [BH][D][T] (kv-slot-permuted) directly. Address formulas transcribed
// from the proven k_repack_qk / k_transpose_v kernels.
// M=8192, N=3072, K=1024 fixed.

__global__ __launch_bounds__(256, 2)
void k_gemm_qkv(const unsigned short* __restrict__ A, const unsigned short* __restrict__ Bt,
                unsigned short* __restrict__ q, unsigned short* __restrict__ kk,
                unsigned short* __restrict__ vt) {
  const int K = 1024;
  __shared__ __align__(16) unsigned short As[128 * 32];
  __shared__ __align__(16) unsigned short Bs[128 * 32];
  const int tid = threadIdx.x;
  const int w = tid >> 6, l = tid & 63;
  const int wr = w >> 1, wc = w & 1;
  const int lo = l & 15, hi = l >> 4;
  const int m0 = blockIdx.y * 128, n0 = blockIdx.x * 128;
  const int srow = l >> 2;
  const int scol = (l & 3) * 8;
  const size_t a_base = (size_t)(m0 + 2 * w * 16 + srow) * K + scol;
  const size_t b_base = (size_t)(n0 + 2 * w * 16 + srow) * K + scol;

  f32x4 acc[4][4] = {};

  for (int kt = 0; kt < K; kt += 32) {
    async16(A + a_base + kt, &As[(2 * w) * 512]);
    async16(A + a_base + kt + (size_t)16 * K, &As[(2 * w + 1) * 512]);
    async16(Bt + b_base + kt, &Bs[(2 * w) * 512]);
    async16(Bt + b_base + kt + (size_t)16 * K, &Bs[(2 * w + 1) * 512]);
    __syncthreads();
    u16x8 af[4], bfv[4];
#pragma unroll
    for (int mi = 0; mi < 4; ++mi)
      af[mi] = *(const u16x8*)&As[(wr * 64 + mi * 16 + lo) * 32 + hi * 8];
#pragma unroll
    for (int ni = 0; ni < 4; ++ni)
      bfv[ni] = *(const u16x8*)&Bs[(wc * 64 + ni * 16 + lo) * 32 + hi * 8];
#pragma unroll
    for (int mi = 0; mi < 4; ++mi)
#pragma unroll
      for (int ni = 0; ni < 4; ++ni)
        acc[mi][ni] = mfma16(af[mi], bfv[ni], acc[mi][ni]);
    __syncthreads();
  }
#pragma unroll
  for (int mi = 0; mi < 4; ++mi) {
#pragma unroll
    for (int ni = 0; ni < 4; ++ni) {
      const int col = n0 + wc * 64 + ni * 16 + lo;      // [0,3072)
      const int sel = col >> 10;                        // 0=Q 1=K 2=V
      const int cc2 = col & 1023;
      const int h = cc2 >> 6, d = cc2 & 63;
      const int row0 = m0 + wr * 64 + mi * 16 + hi * 4; // quad-aligned
      const int b = row0 >> 11, t0q = row0 & 2047;
      const int bh = b * 16 + h;
      if (sel < 2) {
        unsigned short* dst = (sel == 0) ? q : kk;
#pragma unroll
        for (int r = 0; r < 4; ++r)
          dst[((size_t)bh * 2048 + t0q + r) * 64 + d] = f2b(acc[mi][ni][r]);
      } else {
        // V^T with slot permutation: time t -> (t&~31) + sbase(t&31) + (t&3)
        const int c32 = t0q & 31;                       // quad-aligned
        const int sbase = (c32 < 16) ? (2 * c32) : (2 * (c32 - 16) + 4);
        u16x4 pk;
#pragma unroll
        for (int r = 0; r < 4; ++r) pk[r] = f2b(acc[mi][ni][r]);
        *(u16x4*)&vt[((size_t)bh * 64 + d) * 2048 + (t0q & ~31) + sbase] = pk;
      }
    }
  }
}

// ---------------- flash attention (causal), swapped-QK^T, zero-shuffle PV ----
// Wave = 32 q-rows (one strip). Scores for q-row lo live in 4-lane group
// {lo,lo+16,lo+32,lo+48}; reduction = in-lane tree + shfl_xor(16,32).
// PV B-fragment is fully in-lane thanks to the V^T slot permutation.
// r18 delta vs r17 (sole change): T5 s_setprio(1)/(0) wrapped around the
// MFMA clusters — scheduler hint only, no semantic change. m191: +4-7% on
// attention with independent waves at different loop phases (our structure).

DEV void attn_strip(const unsigned short* __restrict__ Q,
                    const unsigned short* __restrict__ Kp,
                    const unsigned short* __restrict__ Vp,
                    unsigned short* __restrict__ AO,
                    int bh, int q0, int lo, int g) {
  const size_t base = (size_t)bh * 2048 * 64;
  const unsigned short* Kb = Kp + base;
  const unsigned short* Vb = Vp + base;

  u16x8 qf[2][2];
#pragma unroll
  for (int qh = 0; qh < 2; ++qh)
#pragma unroll
    for (int dh = 0; dh < 2; ++dh)
      qf[qh][dh] = *(const u16x8*)&Q[base + (size_t)(q0 + qh * 16 + lo) * 64 + dh * 32 + g * 8];

  f32x4 o[2][4] = {};
  float m[2] = {-INFINITY, -INFINITY};
  float lsum[2] = {0.f, 0.f};

  const int nb = q0 / 32 + 1;
  u16x8 kA[2][2], kN[2][2];
#pragma unroll
  for (int kvh = 0; kvh < 2; ++kvh)
#pragma unroll
    for (int dh = 0; dh < 2; ++dh)
      kA[kvh][dh] = *(const u16x8*)&Kb[(size_t)(kvh * 16 + lo) * 64 + dh * 32 + g * 8];

  for (int blk = 0; blk < nb; ++blk) {
    const int kv0 = blk * 32;
    if (blk + 1 < nb) {
      const int kn = kv0 + 32;
#pragma unroll
      for (int kvh = 0; kvh < 2; ++kvh)
#pragma unroll
        for (int dh = 0; dh < 2; ++dh)
          kN[kvh][dh] = *(const u16x8*)&Kb[(size_t)(kn + kvh * 16 + lo) * 64 + dh * 32 + g * 8];
    }
    u16x8 vf[4];
#pragma unroll
    for (int n = 0; n < 4; ++n)
      vf[n] = *(const u16x8*)&Vb[(size_t)(n * 16 + lo) * 2048 + kv0 + g * 8];

    f32x4 sT[2][2];
    __builtin_amdgcn_s_setprio(1);
#pragma unroll
    for (int qh = 0; qh < 2; ++qh)
#pragma unroll
      for (int kvh = 0; kvh < 2; ++kvh) {
        f32x4 z = {};
        z = mfma16(kA[kvh][0], qf[qh][0], z);
        z = mfma16(kA[kvh][1], qf[qh][1], z);
        sT[qh][kvh] = z;
      }
    __builtin_amdgcn_s_setprio(0);

    const bool lastblk = (blk == nb - 1);
#pragma unroll
    for (int qh = 0; qh < 2; ++qh) {
      float s[8];
#pragma unroll
      for (int kvh = 0; kvh < 2; ++kvh)
#pragma unroll
        for (int r = 0; r < 4; ++r)
          s[kvh * 4 + r] = sT[qh][kvh][r] * 0.125f;
      if (lastblk) {
        const int qi = qh * 16 + lo;
#pragma unroll
        for (int kvh = 0; kvh < 2; ++kvh)
#pragma unroll
          for (int r = 0; r < 4; ++r)
            if (kvh * 16 + 4 * g + r > qi) s[kvh * 4 + r] = -INFINITY;
      }
      float mx = fmaxf(fmaxf(fmaxf(s[0], s[1]), fmaxf(s[2], s[3])),
                       fmaxf(fmaxf(s[4], s[5]), fmaxf(s[6], s[7])));
      mx = fmaxf(mx, __shfl_xor(mx, 16));
      mx = fmaxf(mx, __shfl_xor(mx, 32));
      float corr = 1.0f;
      if (!__all(mx <= m[qh] + 8.0f)) {
        float mn = fmaxf(m[qh], mx);
        corr = __expf(m[qh] - mn);
        m[qh] = mn;
#pragma unroll
        for (int n = 0; n < 4; ++n)
#pragma unroll
          for (int r = 0; r < 4; ++r) o[qh][n][r] *= corr;
      }
      float pe[8];
#pragma unroll
      for (int i = 0; i < 8; ++i) pe[i] = __expf(s[i] - m[qh]);
      float rs = ((pe[0] + pe[1]) + (pe[2] + pe[3])) + ((pe[4] + pe[5]) + (pe[6] + pe[7]));
      rs += __shfl_xor(rs, 16);
      rs += __shfl_xor(rs, 32);
      lsum[qh] = lsum[qh] * corr + rs;

      // B-fragment is in-lane: slot j of lane (lo,g) is exactly pe[j]
      unsigned tw[4];
      tw[0] = cvtpk(pe[0], pe[1]);
      tw[1] = cvtpk(pe[2], pe[3]);
      tw[2] = cvtpk(pe[4], pe[5]);
      tw[3] = cvtpk(pe[6], pe[7]);
      u16x8 pB;
#pragma unroll
      for (int i = 0; i < 4; ++i) {
        pB[2 * i] = (unsigned short)(tw[i] & 0xffffu);
        pB[2 * i + 1] = (unsigned short)(tw[i] >> 16);
      }
      __builtin_amdgcn_s_setprio(1);
#pragma unroll
      for (int n = 0; n < 4; ++n) o[qh][n] = mfma16(vf[n], pB, o[qh][n]);
      __builtin_amdgcn_s_setprio(0);
    }

    if (blk + 1 < nb) {
#pragma unroll
      for (int kvh = 0; kvh < 2; ++kvh)
#pragma unroll
        for (int dh = 0; dh < 2; ++dh) kA[kvh][dh] = kN[kvh][dh];
    }
  }

  const int b = bh >> 4, h = bh & 15;
#pragma unroll
  for (int qh = 0; qh < 2; ++qh) {
    const float inv = 1.0f / lsum[qh];
    const int t = q0 + qh * 16 + lo;
    const size_t row = (size_t)(b * 2048 + t);
#pragma unroll
    for (int n = 0; n < 4; ++n) {
      u16x4 pk;
#pragma unroll
      for (int r = 0; r < 4; ++r) pk[r] = f2b(o[qh][n][r] * inv);
      *(u16x4*)&AO[row * 1024 + h * 64 + n * 16 + 4 * g] = pk;
    }
  }
}

// 512 blocks x 256 threads: 4 INDEPENDENT mirror-pair waves per workgroup.
// Wave w of block i: pair p = ((i>>3)&7)*4+w of head bh=(i&7)*8+(i>>6);
// runs strips p and 63-p = uniform 65 iters/wave (r8-proven balance).
// No LDS, no sync, no cross-wave state.
__global__ __launch_bounds__(256)
void k_attn(const unsigned short* __restrict__ Q, const unsigned short* __restrict__ K,
            const unsigned short* __restrict__ V, unsigned short* __restrict__ AO) {
  const int tid = threadIdx.x;
  const int w = tid >> 6, l = tid & 63;
  const int lo = l & 15, g = l >> 4;
  const int i = blockIdx.x;                 // [0,512)
  const int bh = (i & 7) * 8 + (i >> 6);    // XCD x owns bh in [8x,8x+8)
  const int p = ((i >> 3) & 7) * 4 + w;     // [0,32)
  attn_strip(Q, K, V, AO, bh, p * 32, lo, g);
  attn_strip(Q, K, V, AO, bh, (63 - p) * 32, lo, g);
}

// ---------------- launcher ----------------

extern "C" void kernel_launch(void* const* d_in, const int* in_sizes, int n_in,
                              void* d_out, int out_size, void* d_ws, size_t ws_size,
                              hipStream_t stream) {
  (void)in_sizes; (void)n_in; (void)out_size;
  const float* x    = (const float*)d_in[0];
  const float* Wqkv = (const float*)d_in[1];
  const float* Wout = (const float*)d_in[2];
  float* out = (float*)d_out;

  const size_t OFF_XB  = 0;
  const size_t OFF_WQT = 16777216;
  const size_t OFF_WOT = 23068672;
  const size_t OFF_Q   = 25165824;
  const size_t OFF_K   = 41943040;
  const size_t OFF_VT  = 58720256;
  const size_t OFF_AO  = 75497472;
  const size_t NEED    = 125829120;
  if (ws_size < NEED) return;

  char* ws = (char*)d_ws;
  unsigned short* xb  = (unsigned short*)(ws + OFF_XB);
  unsigned short* wqT = (unsigned short*)(ws + OFF_WQT);
  unsigned short* woT = (unsigned short*)(ws + OFF_WOT);
  unsigned short* q   = (unsigned short*)(ws + OFF_Q);
  unsigned short* kk  = (unsigned short*)(ws + OFF_K);
  unsigned short* vt  = (unsigned short*)(ws + OFF_VT);
  unsigned short* ao  = (unsigned short*)(ws + OFF_AO);

  k_convert<<<4096, 256, 0, stream>>>(x, xb, 1048576);
  dim3 tb(32, 8);
  k_transpose<<<dim3(96, 32), tb, 0, stream>>>(Wqkv, wqT, 1024, 3072);
  k_transpose<<<dim3(32, 32), tb, 0, stream>>>(Wout, woT, 1024, 1024);
  k_gemm_qkv<<<dim3(24, 64), 256, 0, stream>>>(xb, wqT, q, kk, vt);
  k_attn<<<512, 256, 0, stream>>>(q, kk, vt, ao);
  k_gemm_bt<float><<<dim3(8, 64), 256, 0, stream>>>(ao, woT, out, 8192, 1024, 1024, 1024);
}

// Round 20
// 230.979 us; speedup vs baseline: 1.0028x; 1.0028x over previous
//
#include <hip/hip_runtime.h>
#include <hip/hip_bf16.h>

#define DEV __device__ __forceinline__

typedef __attribute__((ext_vector_type(4))) float f32x4;
typedef __attribute__((ext_vector_type(8))) __bf16 bf16x8;
typedef __attribute__((ext_vector_type(8))) unsigned short u16x8;
typedef __attribute__((ext_vector_type(4))) unsigned short u16x4;

// round-to-nearest-even f32 -> bf16
DEV unsigned short f2b(float x) {
  unsigned int u = __builtin_bit_cast(unsigned int, x);
  unsigned int r = (u + 0x7fffu + ((u >> 16) & 1u)) >> 16;
  return (unsigned short)r;
}

// packed f32x2 -> bf16x2 (RNE), single instruction
DEV unsigned int cvtpk(float a, float b) {
  unsigned int r;
  asm("v_cvt_pk_bf16_f32 %0, %1, %2" : "=v"(r) : "v"(a), "v"(b));
  return r;
}

DEV f32x4 mfma16(u16x8 a, u16x8 b, f32x4 c) {
  return __builtin_amdgcn_mfma_f32_16x16x32_bf16(
      __builtin_bit_cast(bf16x8, a), __builtin_bit_cast(bf16x8, b), c, 0, 0, 0);
}

// async global->LDS, 16B per lane; LDS dest is wave-uniform base + lane*16
DEV void async16(const unsigned short* g, unsigned short* l) {
  __builtin_amdgcn_global_load_lds(
      (const __attribute__((address_space(1))) void*)g,
      (__attribute__((address_space(3))) void*)l, 16, 0, 0);
}

// ---------------- conversion / transpose ----------------

__global__ void k_convert(const float* __restrict__ in, unsigned short* __restrict__ out, int n8) {
  int i = blockIdx.x * 256 + threadIdx.x;
  if (i >= n8) return;
  const float4* p = (const float4*)in + (size_t)i * 2;
  float4 a = p[0], b = p[1];
  u16x8 v;
  v[0] = f2b(a.x); v[1] = f2b(a.y); v[2] = f2b(a.z); v[3] = f2b(a.w);
  v[4] = f2b(b.x); v[5] = f2b(b.y); v[6] = f2b(b.z); v[7] = f2b(b.w);
  *((u16x8*)out + i) = v;
}

// in[R][Cc] f32 -> out[Cc][R] bf16
__global__ void k_transpose(const float* __restrict__ in, unsigned short* __restrict__ out,
                            int R, int Cc) {
  __shared__ float tile[32][33];
  int bx = blockIdx.x * 32, by = blockIdx.y * 32;
  int tx = threadIdx.x, ty = threadIdx.y;
#pragma unroll
  for (int i = 0; i < 32; i += 8)
    tile[ty + i][tx] = in[(size_t)(by + ty + i) * Cc + bx + tx];
  __syncthreads();
#pragma unroll
  for (int i = 0; i < 32; i += 8)
    out[(size_t)(bx + ty + i) * R + by + tx] = f2b(tile[tx][ty + i]);
}

// ---------------- GEMM: C[M][N] = A[M][K] * Bt[N][K]^T ----------------

template <typename OutT>
__global__ __launch_bounds__(256, 2)
void k_gemm_bt(const unsigned short* __restrict__ A, const unsigned short* __restrict__ Bt,
               OutT* __restrict__ C, int M, int N, int K, int ldc) {
  __shared__ __align__(16) unsigned short As[128 * 32];
  __shared__ __align__(16) unsigned short Bs[128 * 32];
  const int tid = threadIdx.x;
  const int w = tid >> 6, l = tid & 63;
  const int wr = w >> 1, wc = w & 1;
  const int lo = l & 15, hi = l >> 4;
  const int m0 = blockIdx.y * 128, n0 = blockIdx.x * 128;
  const int srow = l >> 2;            // row within 16-row segment
  const int scol = (l & 3) * 8;       // k elements
  const size_t a_base = (size_t)(m0 + 2 * w * 16 + srow) * K + scol;
  const size_t b_base = (size_t)(n0 + 2 * w * 16 + srow) * K + scol;

  f32x4 acc[4][4] = {};

  for (int kt = 0; kt < K; kt += 32) {
    async16(A + a_base + kt, &As[(2 * w) * 512]);
    async16(A + a_base + kt + (size_t)16 * K, &As[(2 * w + 1) * 512]);
    async16(Bt + b_base + kt, &Bs[(2 * w) * 512]);
    async16(Bt + b_base + kt + (size_t)16 * K, &Bs[(2 * w + 1) * 512]);
    __syncthreads();
    u16x8 af[4], bfv[4];
#pragma unroll
    for (int mi = 0; mi < 4; ++mi)
      af[mi] = *(const u16x8*)&As[(wr * 64 + mi * 16 + lo) * 32 + hi * 8];
#pragma unroll
    for (int ni = 0; ni < 4; ++ni)
      bfv[ni] = *(const u16x8*)&Bs[(wc * 64 + ni * 16 + lo) * 32 + hi * 8];
#pragma unroll
    for (int mi = 0; mi < 4; ++mi)
#pragma unroll
      for (int ni = 0; ni < 4; ++ni)
        acc[mi][ni] = mfma16(af[mi], bfv[ni], acc[mi][ni]);
    __syncthreads();
  }
#pragma unroll
  for (int mi = 0; mi < 4; ++mi) {
#pragma unroll
    for (int ni = 0; ni < 4; ++ni) {
      int col = n0 + wc * 64 + ni * 16 + lo;
#pragma unroll
      for (int r = 0; r < 4; ++r) {
        int row = m0 + wr * 64 + mi * 16 + hi * 4 + r;
        float v = acc[mi][ni][r];
        if constexpr (sizeof(OutT) == 4)
          C[(size_t)row * ldc + col] = v;
        else
          C[(size_t)row * ldc + col] = f2b(v);
      }
    }
  }
}

// ---- QKV GEMM with fused repack epilogue: writes Q,K [BH][T][D] and
// V^T [BH][D][T] (kv-slot-permuted) directly. Address formulas transcribed
// from the proven k_repack_qk / k_transpose_v kernels.
// M=8192, N=3072, K=1024 fixed.

__global__ __launch_bounds__(256, 2)
void k_gemm_qkv(const unsigned short* __restrict__ A, const unsigned short* __restrict__ Bt,
                unsigned short* __restrict__ q, unsigned short* __restrict__ kk,
                unsigned short* __restrict__ vt) {
  const int K = 1024;
  __shared__ __align__(16) unsigned short As[128 * 32];
  __shared__ __align__(16) unsigned short Bs[128 * 32];
  const int tid = threadIdx.x;
  const int w = tid >> 6, l = tid & 63;
  const int wr = w >> 1, wc = w & 1;
  const int lo = l & 15, hi = l >> 4;
  const int m0 = blockIdx.y * 128, n0 = blockIdx.x * 128;
  const int srow = l >> 2;
  const int scol = (l & 3) * 8;
  const size_t a_base = (size_t)(m0 + 2 * w * 16 + srow) * K + scol;
  const size_t b_base = (size_t)(n0 + 2 * w * 16 + srow) * K + scol;

  f32x4 acc[4][4] = {};

  for (int kt = 0; kt < K; kt += 32) {
    async16(A + a_base + kt, &As[(2 * w) * 512]);
    async16(A + a_base + kt + (size_t)16 * K, &As[(2 * w + 1) * 512]);
    async16(Bt + b_base + kt, &Bs[(2 * w) * 512]);
    async16(Bt + b_base + kt + (size_t)16 * K, &Bs[(2 * w + 1) * 512]);
    __syncthreads();
    u16x8 af[4], bfv[4];
#pragma unroll
    for (int mi = 0; mi < 4; ++mi)
      af[mi] = *(const u16x8*)&As[(wr * 64 + mi * 16 + lo) * 32 + hi * 8];
#pragma unroll
    for (int ni = 0; ni < 4; ++ni)
      bfv[ni] = *(const u16x8*)&Bs[(wc * 64 + ni * 16 + lo) * 32 + hi * 8];
#pragma unroll
    for (int mi = 0; mi < 4; ++mi)
#pragma unroll
      for (int ni = 0; ni < 4; ++ni)
        acc[mi][ni] = mfma16(af[mi], bfv[ni], acc[mi][ni]);
    __syncthreads();
  }
#pragma unroll
  for (int mi = 0; mi < 4; ++mi) {
#pragma unroll
    for (int ni = 0; ni < 4; ++ni) {
      const int col = n0 + wc * 64 + ni * 16 + lo;      // [0,3072)
      const int sel = col >> 10;                        // 0=Q 1=K 2=V
      const int cc2 = col & 1023;
      const int h = cc2 >> 6, d = cc2 & 63;
      const int row0 = m0 + wr * 64 + mi * 16 + hi * 4; // quad-aligned
      const int b = row0 >> 11, t0q = row0 & 2047;
      const int bh = b * 16 + h;
      if (sel < 2) {
        unsigned short* dst = (sel == 0) ? q : kk;
#pragma unroll
        for (int r = 0; r < 4; ++r)
          dst[((size_t)bh * 2048 + t0q + r) * 64 + d] = f2b(acc[mi][ni][r]);
      } else {
        // V^T with slot permutation: time t -> (t&~31) + sbase(t&31) + (t&3)
        const int c32 = t0q & 31;                       // quad-aligned
        const int sbase = (c32 < 16) ? (2 * c32) : (2 * (c32 - 16) + 4);
        u16x4 pk;
#pragma unroll
        for (int r = 0; r < 4; ++r) pk[r] = f2b(acc[mi][ni][r]);
        *(u16x4*)&vt[((size_t)bh * 64 + d) * 2048 + (t0q & ~31) + sbase] = pk;
      }
    }
  }
}

// ---------------- flash attention (causal), swapped-QK^T, zero-shuffle PV ----
// Wave = 32 q-rows (one strip). Scores for q-row lo live in 4-lane group
// {lo,lo+16,lo+32,lo+48}; reduction = in-lane tree + shfl_xor(16,32).
// PV B-fragment is fully in-lane thanks to the V^T slot permutation.
// FINAL: r17-verbatim (twice-verified PASS). Session notes:
//  - permlane{16,32}_swap SELF-swap (a==b) is UNSAFE: operands alias to one
//    register -> in-place half-exchange destroys own value (r5/r6/r19 NaN).
//  - s_setprio on lockstep mirror-pair waves: neutral (r18; m190-like null).
//  - wave-count/chain-length restructures (r9-r12, r15, r16): codegen-
//    sensitive correctness flips; abandoned under session risk budget.

DEV void attn_strip(const unsigned short* __restrict__ Q,
                    const unsigned short* __restrict__ Kp,
                    const unsigned short* __restrict__ Vp,
                    unsigned short* __restrict__ AO,
                    int bh, int q0, int lo, int g) {
  const size_t base = (size_t)bh * 2048 * 64;
  const unsigned short* Kb = Kp + base;
  const unsigned short* Vb = Vp + base;

  u16x8 qf[2][2];
#pragma unroll
  for (int qh = 0; qh < 2; ++qh)
#pragma unroll
    for (int dh = 0; dh < 2; ++dh)
      qf[qh][dh] = *(const u16x8*)&Q[base + (size_t)(q0 + qh * 16 + lo) * 64 + dh * 32 + g * 8];

  f32x4 o[2][4] = {};
  float m[2] = {-INFINITY, -INFINITY};
  float lsum[2] = {0.f, 0.f};

  const int nb = q0 / 32 + 1;
  u16x8 kA[2][2], kN[2][2];
#pragma unroll
  for (int kvh = 0; kvh < 2; ++kvh)
#pragma unroll
    for (int dh = 0; dh < 2; ++dh)
      kA[kvh][dh] = *(const u16x8*)&Kb[(size_t)(kvh * 16 + lo) * 64 + dh * 32 + g * 8];

  for (int blk = 0; blk < nb; ++blk) {
    const int kv0 = blk * 32;
    if (blk + 1 < nb) {
      const int kn = kv0 + 32;
#pragma unroll
      for (int kvh = 0; kvh < 2; ++kvh)
#pragma unroll
        for (int dh = 0; dh < 2; ++dh)
          kN[kvh][dh] = *(const u16x8*)&Kb[(size_t)(kn + kvh * 16 + lo) * 64 + dh * 32 + g * 8];
    }
    u16x8 vf[4];
#pragma unroll
    for (int n = 0; n < 4; ++n)
      vf[n] = *(const u16x8*)&Vb[(size_t)(n * 16 + lo) * 2048 + kv0 + g * 8];

    f32x4 sT[2][2];
#pragma unroll
    for (int qh = 0; qh < 2; ++qh)
#pragma unroll
      for (int kvh = 0; kvh < 2; ++kvh) {
        f32x4 z = {};
        z = mfma16(kA[kvh][0], qf[qh][0], z);
        z = mfma16(kA[kvh][1], qf[qh][1], z);
        sT[qh][kvh] = z;
      }

    const bool lastblk = (blk == nb - 1);
#pragma unroll
    for (int qh = 0; qh < 2; ++qh) {
      float s[8];
#pragma unroll
      for (int kvh = 0; kvh < 2; ++kvh)
#pragma unroll
        for (int r = 0; r < 4; ++r)
          s[kvh * 4 + r] = sT[qh][kvh][r] * 0.125f;
      if (lastblk) {
        const int qi = qh * 16 + lo;
#pragma unroll
        for (int kvh = 0; kvh < 2; ++kvh)
#pragma unroll
          for (int r = 0; r < 4; ++r)
            if (kvh * 16 + 4 * g + r > qi) s[kvh * 4 + r] = -INFINITY;
      }
      float mx = fmaxf(fmaxf(fmaxf(s[0], s[1]), fmaxf(s[2], s[3])),
                       fmaxf(fmaxf(s[4], s[5]), fmaxf(s[6], s[7])));
      mx = fmaxf(mx, __shfl_xor(mx, 16));
      mx = fmaxf(mx, __shfl_xor(mx, 32));
      float corr = 1.0f;
      if (!__all(mx <= m[qh] + 8.0f)) {
        float mn = fmaxf(m[qh], mx);
        corr = __expf(m[qh] - mn);
        m[qh] = mn;
#pragma unroll
        for (int n = 0; n < 4; ++n)
#pragma unroll
          for (int r = 0; r < 4; ++r) o[qh][n][r] *= corr;
      }
      float pe[8];
#pragma unroll
      for (int i = 0; i < 8; ++i) pe[i] = __expf(s[i] - m[qh]);
      float rs = ((pe[0] + pe[1]) + (pe[2] + pe[3])) + ((pe[4] + pe[5]) + (pe[6] + pe[7]));
      rs += __shfl_xor(rs, 16);
      rs += __shfl_xor(rs, 32);
      lsum[qh] = lsum[qh] * corr + rs;

      // B-fragment is in-lane: slot j of lane (lo,g) is exactly pe[j]
      unsigned tw[4];
      tw[0] = cvtpk(pe[0], pe[1]);
      tw[1] = cvtpk(pe[2], pe[3]);
      tw[2] = cvtpk(pe[4], pe[5]);
      tw[3] = cvtpk(pe[6], pe[7]);
      u16x8 pB;
#pragma unroll
      for (int i = 0; i < 4; ++i) {
        pB[2 * i] = (unsigned short)(tw[i] & 0xffffu);
        pB[2 * i + 1] = (unsigned short)(tw[i] >> 16);
      }
#pragma unroll
      for (int n = 0; n < 4; ++n) o[qh][n] = mfma16(vf[n], pB, o[qh][n]);
    }

    if (blk + 1 < nb) {
#pragma unroll
      for (int kvh = 0; kvh < 2; ++kvh)
#pragma unroll
        for (int dh = 0; dh < 2; ++dh) kA[kvh][dh] = kN[kvh][dh];
    }
  }

  const int b = bh >> 4, h = bh & 15;
#pragma unroll
  for (int qh = 0; qh < 2; ++qh) {
    const float inv = 1.0f / lsum[qh];
    const int t = q0 + qh * 16 + lo;
    const size_t row = (size_t)(b * 2048 + t);
#pragma unroll
    for (int n = 0; n < 4; ++n) {
      u16x4 pk;
#pragma unroll
      for (int r = 0; r < 4; ++r) pk[r] = f2b(o[qh][n][r] * inv);
      *(u16x4*)&AO[row * 1024 + h * 64 + n * 16 + 4 * g] = pk;
    }
  }
}

// 512 blocks x 256 threads: 4 INDEPENDENT mirror-pair waves per workgroup.
// Wave w of block i: pair p = ((i>>3)&7)*4+w of head bh=(i&7)*8+(i>>6);
// runs strips p and 63-p = uniform 65 iters/wave (r8-proven balance).
// No LDS, no sync, no cross-wave state.
__global__ __launch_bounds__(256)
void k_attn(const unsigned short* __restrict__ Q, const unsigned short* __restrict__ K,
            const unsigned short* __restrict__ V, unsigned short* __restrict__ AO) {
  const int tid = threadIdx.x;
  const int w = tid >> 6, l = tid & 63;
  const int lo = l & 15, g = l >> 4;
  const int i = blockIdx.x;                 // [0,512)
  const int bh = (i & 7) * 8 + (i >> 6);    // XCD x owns bh in [8x,8x+8)
  const int p = ((i >> 3) & 7) * 4 + w;     // [0,32)
  attn_strip(Q, K, V, AO, bh, p * 32, lo, g);
  attn_strip(Q, K, V, AO, bh, (63 - p) * 32, lo, g);
}

// ---------------- launcher ----------------

extern "C" void kernel_launch(void* const* d_in, const int* in_sizes, int n_in,
                              void* d_out, int out_size, void* d_ws, size_t ws_size,
                              hipStream_t stream) {
  (void)in_sizes; (void)n_in; (void)out_size;
  const float* x    = (const float*)d_in[0];
  const float* Wqkv = (const float*)d_in[1];
  const float* Wout = (const float*)d_in[2];
  float* out = (float*)d_out;

  const size_t OFF_XB  = 0;
  const size_t OFF_WQT = 16777216;
  const size_t OFF_WOT = 23068672;
  const size_t OFF_Q   = 25165824;
  const size_t OFF_K   = 41943040;
  const size_t OFF_VT  = 58720256;
  const size_t OFF_AO  = 75497472;
  const size_t NEED    = 125829120;
  if (ws_size < NEED) return;

  char* ws = (char*)d_ws;
  unsigned short* xb  = (unsigned short*)(ws + OFF_XB);
  unsigned short* wqT = (unsigned short*)(ws + OFF_WQT);
  unsigned short* woT = (unsigned short*)(ws + OFF_WOT);
  unsigned short* q   = (unsigned short*)(ws + OFF_Q);
  unsigned short* kk  = (unsigned short*)(ws + OFF_K);
  unsigned short* vt  = (unsigned short*)(ws + OFF_VT);
  unsigned short* ao  = (unsigned short*)(ws + OFF_AO);

  k_convert<<<4096, 256, 0, stream>>>(x, xb, 1048576);
  dim3 tb(32, 8);
  k_transpose<<<dim3(96, 32), tb, 0, stream>>>(Wqkv, wqT, 1024, 3072);
  k_transpose<<<dim3(32, 32), tb, 0, stream>>>(Wout, woT, 1024, 1024);
  k_gemm_qkv<<<dim3(24, 64), 256, 0, stream>>>(xb, wqT, q, kk, vt);
  k_attn<<<512, 256, 0, stream>>>(q, kk, vt, ao);
  k_gemm_bt<float><<<dim3(8, 64), 256, 0, stream>>>(ao, woT, out, 8192, 1024, 1024, 1024);
}